// Round 18
// baseline (605.216 us; speedup 1.0000x reference)
//
#include <hip/hip_runtime.h>
#include <math.h>

#define SELF_VAL (-5e4f)
#define GAP_THR 0.004f

typedef __attribute__((ext_vector_type(8))) short bf16x8;
typedef __attribute__((ext_vector_type(4))) float f32x4;

__device__ __forceinline__ unsigned short f2bf(float x) {
    unsigned b = __float_as_uint(x);
    b += 0x7FFFu + ((b >> 16) & 1u);
    return (unsigned short)(b >> 16);
}
__device__ __forceinline__ float bf2f(unsigned short h) {
    return __uint_as_float(((unsigned)h) << 16);
}
__device__ __forceinline__ unsigned pk2(unsigned short a, unsigned short b) {
    return (unsigned)a | ((unsigned)b << 16);
}

// ---------------- K0: re-layout rotations -> rotT2[h][k][col]  (4 x 64 x 256) ----------------
__global__ __launch_bounds__(256) void k_rotT(const float* __restrict__ rot,
                                              float* __restrict__ rotT2)
{
    int idx = blockIdx.x * 256 + threadIdx.x;    // 0..65535
    int h = idx >> 14, k = (idx >> 8) & 63, col = idx & 255;
    rotT2[idx] = rot[k * 1024 + h * 256 + col];
}

// ---------------- K0a: rotations -> split bf16 rotT3{hi,lo}[cglob][k] ----------------
__global__ __launch_bounds__(256) void k_rotsplit(const float* __restrict__ rot,
    unsigned short* __restrict__ rotT3hi, unsigned short* __restrict__ rotT3lo)
{
    int idx = blockIdx.x * 256 + threadIdx.x;    // 0..65535
    int cg = idx >> 6, k = idx & 63;             // cg = h*256 + col
    float v = rot[k * 1024 + cg];
    unsigned short hi = f2bf(v);
    unsigned short lo = f2bf(v - bf2f(hi));
    rotT3hi[idx] = hi;
    rotT3lo[idx] = lo;
}

// ---------------- K0b: Wout -> transposed bf16 WoutT16[n][k] ----------------
__global__ __launch_bounds__(256) void k_woutT(const float* __restrict__ Wout,
                                               unsigned short* __restrict__ WoutT16)
{
    int idx = blockIdx.x * 256 + threadIdx.x;    // 0..262143
    int n = idx >> 9, k = idx & 511;
    WoutT16[idx] = f2bf(Wout[(size_t)k * 512 + n]);
}

// ---------------- K0c: Wv -> transposed bf16 WvT16[n][k] ----------------
__global__ __launch_bounds__(256) void k_wvT(const float* __restrict__ Wv,
                                             unsigned short* __restrict__ WvT16)
{
    int idx = blockIdx.x * 256 + threadIdx.x;    // 0..262143
    int n = idx >> 9, k = idx & 511;
    WvT16[idx] = f2bf(Wv[(size_t)k * 512 + n]);
}

// ---------------- K0d: Q -> bf16 row-major Q16 ----------------
__global__ __launch_bounds__(256) void k_q16(const float* __restrict__ Q,
                                             unsigned short* __restrict__ Q16)
{
    int idx = blockIdx.x * 256 + threadIdx.x;    // 8 elems each
    const float* src = Q + (size_t)idx * 8;
    float4 v0 = *(const float4*)src;
    float4 v1 = *(const float4*)(src + 4);
    union { unsigned short s[8]; uint4 v; } ob;
    ob.s[0]=f2bf(v0.x); ob.s[1]=f2bf(v0.y); ob.s[2]=f2bf(v0.z); ob.s[3]=f2bf(v0.w);
    ob.s[4]=f2bf(v1.x); ob.s[5]=f2bf(v1.y); ob.s[6]=f2bf(v1.z); ob.s[7]=f2bf(v1.w);
    *(uint4*)(Q16 + (size_t)idx * 8) = ob.v;
}

// ---------------- K1: qk GEMM (f32, 128x128, 8x8/thread, T14 dbuf) ----------------
// + fused rnorm + fused split-bf16 emit (qk16hi/lo) for the MFMA hash.
__global__ __launch_bounds__(256) void k_gemm_qk(
    const float* __restrict__ Q, const float* __restrict__ Wqk,
    float* __restrict__ qk, float* __restrict__ rnorm,
    unsigned short* __restrict__ qk16hi, unsigned short* __restrict__ qk16lo)
{
    __shared__ float As[16][132];   // transposed: As[k][m]
    __shared__ float Bs[16][132];
    const int bx = blockIdx.x;
    const int mt = bx >> 2, nt = bx & 3;
    const int m0 = mt * 128, n0 = nt * 128;
    const int tid = threadIdx.x;
    const int ty = tid >> 4, tx = tid & 15;
    const float* Bsrc = Wqk + n0;
    const int ar0 = tid >> 2, acq = (tid & 3) * 4;
    const int ar1 = 64 + (tid >> 2);
    const int bk0 = tid >> 5, bnq = (tid & 31) * 4;
    const int bk1 = 8 + (tid >> 5);
    const float* Aptr0 = Q + (size_t)(m0 + ar0) * 512 + acq;
    const float* Aptr1 = Q + (size_t)(m0 + ar1) * 512 + acq;
    const float* Bptr0 = Bsrc + (size_t)bk0 * 512 + bnq;
    const float* Bptr1 = Bsrc + (size_t)bk1 * 512 + bnq;
    float acc[8][8] = {};
    float4 a0 = *(const float4*)(Aptr0);
    float4 a1 = *(const float4*)(Aptr1);
    float4 b0 = *(const float4*)(Bptr0);
    float4 b1 = *(const float4*)(Bptr1);
    for (int k0 = 0; k0 < 512; k0 += 16) {
        As[acq+0][ar0]=a0.x; As[acq+1][ar0]=a0.y; As[acq+2][ar0]=a0.z; As[acq+3][ar0]=a0.w;
        As[acq+0][ar1]=a1.x; As[acq+1][ar1]=a1.y; As[acq+2][ar1]=a1.z; As[acq+3][ar1]=a1.w;
        *(float4*)&Bs[bk0][bnq] = b0;
        *(float4*)&Bs[bk1][bnq] = b1;
        __syncthreads();
        if (k0 + 16 < 512) {
            a0 = *(const float4*)(Aptr0 + k0 + 16);
            a1 = *(const float4*)(Aptr1 + k0 + 16);
            b0 = *(const float4*)(Bptr0 + (size_t)(k0 + 16) * 512);
            b1 = *(const float4*)(Bptr1 + (size_t)(k0 + 16) * 512);
        }
        #pragma unroll
        for (int kk = 0; kk < 16; kk++) {
            float a_[8], b_[8];
            *(float4*)&a_[0] = *(float4*)&As[kk][ty*4];
            *(float4*)&a_[4] = *(float4*)&As[kk][64 + ty*4];
            *(float4*)&b_[0] = *(float4*)&Bs[kk][tx*4];
            *(float4*)&b_[4] = *(float4*)&Bs[kk][64 + tx*4];
            #pragma unroll
            for (int i = 0; i < 8; i++)
                #pragma unroll
                for (int j = 0; j < 8; j++)
                    acc[i][j] += a_[i] * b_[j];
        }
        __syncthreads();
    }
    #pragma unroll
    for (int ig = 0; ig < 2; ig++) {
        #pragma unroll
        for (int i = 0; i < 4; i++) {
            int row = m0 + ig*64 + ty*4 + i;
            int b = row >> 11, t = row & 2047;
            #pragma unroll
            for (int jg = 0; jg < 2; jg++) {
                int n = n0 + jg*64 + tx*4;
                float4 r4 = make_float4(acc[ig*4+i][jg*4+0], acc[ig*4+i][jg*4+1],
                                        acc[ig*4+i][jg*4+2], acc[ig*4+i][jg*4+3]);
                size_t base = ((size_t)((b*8 + (n>>6))*2048 + t))*64 + (n&63);
                *(float4*)(qk + base) = r4;
                unsigned short h0 = f2bf(r4.x), h1 = f2bf(r4.y), h2 = f2bf(r4.z), h3 = f2bf(r4.w);
                unsigned short l0 = f2bf(r4.x - bf2f(h0)), l1 = f2bf(r4.y - bf2f(h1));
                unsigned short l2 = f2bf(r4.z - bf2f(h2)), l3 = f2bf(r4.w - bf2f(h3));
                uint2 hw = make_uint2(pk2(h0,h1), pk2(h2,h3));
                uint2 lw = make_uint2(pk2(l0,l1), pk2(l2,l3));
                *(uint2*)(qk16hi + base) = hw;
                *(uint2*)(qk16lo + base) = lw;
            }
        }
    }
    // ---- fused rnorm ----
    #pragma unroll
    for (int jg = 0; jg < 2; jg++) {
        int h = (n0 + jg*64) >> 6;
        #pragma unroll
        for (int ig = 0; ig < 2; ig++) {
            #pragma unroll
            for (int i = 0; i < 4; i++) {
                float s = acc[ig*4+i][jg*4+0]*acc[ig*4+i][jg*4+0]
                        + acc[ig*4+i][jg*4+1]*acc[ig*4+i][jg*4+1]
                        + acc[ig*4+i][jg*4+2]*acc[ig*4+i][jg*4+2]
                        + acc[ig*4+i][jg*4+3]*acc[ig*4+i][jg*4+3];
                s += __shfl_xor(s, 1);
                s += __shfl_xor(s, 2);
                s += __shfl_xor(s, 4);
                s += __shfl_xor(s, 8);
                if (tx == 0) {
                    int row = m0 + ig*64 + ty*4 + i;
                    int b = row >> 11, t = row & 2047;
                    rnorm[((size_t)(b*8 + h))*2048 + t] = 1.0f / fmaxf(sqrtf(s), 1e-12f);
                }
            }
        }
    }
}

// ---------------- K1b: v GEMM (bf16 MFMA, 64x64 block, 4 waves 2x2) ----------------
__global__ __launch_bounds__(256) void k_gemm_v(
    const unsigned short* __restrict__ Q16, const unsigned short* __restrict__ WvT16,
    float* __restrict__ vv)
{
    __shared__ unsigned short Asl[64*72];
    __shared__ unsigned short Bsl[64*72];
    const int bx = blockIdx.x;
    const int mt = bx >> 3, nt = bx & 7;
    const int m0 = mt*64, n0 = nt*64;
    const int tid = threadIdx.x;
    const int wid = tid >> 6, lane = tid & 63;
    const int wm = wid >> 1, wn = wid & 1;
    const int l15 = lane & 15, l4 = lane >> 4;
    const int srow = tid >> 2, skb = (tid & 3) * 16;
    f32x4 acc[2][2] = {};
    for (int k0 = 0; k0 < 512; k0 += 64) {
        {
            const unsigned short* asrc = Q16 + (size_t)(m0 + srow)*512 + k0 + skb;
            *(uint4*)&Asl[srow*72 + skb]     = *(const uint4*)asrc;
            *(uint4*)&Asl[srow*72 + skb + 8] = *(const uint4*)(asrc + 8);
            const unsigned short* bsrc = WvT16 + (size_t)(n0 + srow)*512 + k0 + skb;
            *(uint4*)&Bsl[srow*72 + skb]     = *(const uint4*)bsrc;
            *(uint4*)&Bsl[srow*72 + skb + 8] = *(const uint4*)(bsrc + 8);
        }
        __syncthreads();
        #pragma unroll
        for (int kq = 0; kq < 2; kq++) {
            int kb = kq*32 + l4*8;
            bf16x8 a0 = *(bf16x8*)&Asl[(wm*32 +      l15)*72 + kb];
            bf16x8 a1 = *(bf16x8*)&Asl[(wm*32 + 16 + l15)*72 + kb];
            bf16x8 b0 = *(bf16x8*)&Bsl[(wn*32 +      l15)*72 + kb];
            bf16x8 b1 = *(bf16x8*)&Bsl[(wn*32 + 16 + l15)*72 + kb];
            acc[0][0] = __builtin_amdgcn_mfma_f32_16x16x32_bf16(a0, b0, acc[0][0], 0, 0, 0);
            acc[0][1] = __builtin_amdgcn_mfma_f32_16x16x32_bf16(a0, b1, acc[0][1], 0, 0, 0);
            acc[1][0] = __builtin_amdgcn_mfma_f32_16x16x32_bf16(a1, b0, acc[1][0], 0, 0, 0);
            acc[1][1] = __builtin_amdgcn_mfma_f32_16x16x32_bf16(a1, b1, acc[1][1], 0, 0, 0);
        }
        __syncthreads();
    }
    #pragma unroll
    for (int sm = 0; sm < 2; sm++) {
        #pragma unroll
        for (int sn = 0; sn < 2; sn++) {
            int col = n0 + wn*32 + sn*16 + l15;
            int h = col >> 6, d = col & 63;
            #pragma unroll
            for (int r = 0; r < 4; r++) {
                int row = m0 + wm*32 + sm*16 + l4*4 + r;
                int b = row >> 11, t = row & 2047;
                vv[((size_t)((b*8 + h)*2048 + t))*64 + d] = acc[sm][sn][r];
            }
        }
    }
}

// ---------------- K2: hash via split-bf16 MFMA + top-2 gap test + exact f32 fallback ----------------
// rotated = qkhi*rothi + qkhi*rotlo + qklo*rothi  (error <= ~6e-4; gap >= GAP_THR => bucket proven)
__global__ __launch_bounds__(256) void k_hash(
    const float* __restrict__ qk,
    const unsigned short* __restrict__ qk16hi, const unsigned short* __restrict__ qk16lo,
    const float* __restrict__ rotT2,
    const unsigned short* __restrict__ rotT3hi, const unsigned short* __restrict__ rotT3lo,
    unsigned* __restrict__ buckets)
{
    __shared__ unsigned short Ahi[64*72], Alo[64*72], Bhi[64*72], Blo[64*72];
    __shared__ float redv1[128], redv2[128];
    __shared__ unsigned redi1[128];
    __shared__ float fv[256];
    __shared__ unsigned fi[256];
    __shared__ unsigned bidx[64];
    __shared__ int bflag[64];
    const int m0 = blockIdx.x * 64;              // global token row base (bm*2048+t space)
    const int tid = threadIdx.x;
    const int wid = tid >> 6, lane = tid & 63;
    const int wm = wid >> 1, wn = wid & 1;
    const int l15 = lane & 15, l4 = lane >> 4;
    const int srow = tid >> 2, skb = (tid & 3) * 16;
    // ---- stage A (hi/lo) once: rows m0..m0+63, k=0..63 ----
    {
        const unsigned short* ah = qk16hi + (size_t)(m0 + srow)*64 + skb;
        const unsigned short* al = qk16lo + (size_t)(m0 + srow)*64 + skb;
        *(uint4*)&Ahi[srow*72 + skb]     = *(const uint4*)ah;
        *(uint4*)&Ahi[srow*72 + skb + 8] = *(const uint4*)(ah + 8);
        *(uint4*)&Alo[srow*72 + skb]     = *(const uint4*)al;
        *(uint4*)&Alo[srow*72 + skb + 8] = *(const uint4*)(al + 8);
    }
    float bv1[8], bv2[8];
    unsigned bi1[8];
    for (int ch = 0; ch < 16; ch++) {
        const int h = ch >> 2;
        if ((ch & 3) == 0) {
            #pragma unroll
            for (int i = 0; i < 8; i++) { bv1[i] = -3.402823466e38f; bv2[i] = -3.402823466e38f; bi1[i] = 0u; }
        }
        __syncthreads();     // prev chunk B reads done / A staged (ch=0)
        {   // stage B chunk: cols ch*64..+63
            const unsigned short* bh = rotT3hi + (size_t)(ch*64 + srow)*64 + skb;
            const unsigned short* bl = rotT3lo + (size_t)(ch*64 + srow)*64 + skb;
            *(uint4*)&Bhi[srow*72 + skb]     = *(const uint4*)bh;
            *(uint4*)&Bhi[srow*72 + skb + 8] = *(const uint4*)(bh + 8);
            *(uint4*)&Blo[srow*72 + skb]     = *(const uint4*)bl;
            *(uint4*)&Blo[srow*72 + skb + 8] = *(const uint4*)(bl + 8);
        }
        __syncthreads();
        f32x4 acc[2][2] = {};
        #pragma unroll
        for (int kq = 0; kq < 2; kq++) {
            int kb = kq*32 + l4*8;
            bf16x8 ah0 = *(bf16x8*)&Ahi[(wm*32 +      l15)*72 + kb];
            bf16x8 ah1 = *(bf16x8*)&Ahi[(wm*32 + 16 + l15)*72 + kb];
            bf16x8 al0 = *(bf16x8*)&Alo[(wm*32 +      l15)*72 + kb];
            bf16x8 al1 = *(bf16x8*)&Alo[(wm*32 + 16 + l15)*72 + kb];
            bf16x8 bh0 = *(bf16x8*)&Bhi[(wn*32 +      l15)*72 + kb];
            bf16x8 bh1 = *(bf16x8*)&Bhi[(wn*32 + 16 + l15)*72 + kb];
            bf16x8 bl0 = *(bf16x8*)&Blo[(wn*32 +      l15)*72 + kb];
            bf16x8 bl1 = *(bf16x8*)&Blo[(wn*32 + 16 + l15)*72 + kb];
            acc[0][0] = __builtin_amdgcn_mfma_f32_16x16x32_bf16(ah0, bh0, acc[0][0], 0, 0, 0);
            acc[0][1] = __builtin_amdgcn_mfma_f32_16x16x32_bf16(ah0, bh1, acc[0][1], 0, 0, 0);
            acc[1][0] = __builtin_amdgcn_mfma_f32_16x16x32_bf16(ah1, bh0, acc[1][0], 0, 0, 0);
            acc[1][1] = __builtin_amdgcn_mfma_f32_16x16x32_bf16(ah1, bh1, acc[1][1], 0, 0, 0);
            acc[0][0] = __builtin_amdgcn_mfma_f32_16x16x32_bf16(ah0, bl0, acc[0][0], 0, 0, 0);
            acc[0][1] = __builtin_amdgcn_mfma_f32_16x16x32_bf16(ah0, bl1, acc[0][1], 0, 0, 0);
            acc[1][0] = __builtin_amdgcn_mfma_f32_16x16x32_bf16(ah1, bl0, acc[1][0], 0, 0, 0);
            acc[1][1] = __builtin_amdgcn_mfma_f32_16x16x32_bf16(ah1, bl1, acc[1][1], 0, 0, 0);
            acc[0][0] = __builtin_amdgcn_mfma_f32_16x16x32_bf16(al0, bh0, acc[0][0], 0, 0, 0);
            acc[0][1] = __builtin_amdgcn_mfma_f32_16x16x32_bf16(al0, bh1, acc[0][1], 0, 0, 0);
            acc[1][0] = __builtin_amdgcn_mfma_f32_16x16x32_bf16(al1, bh0, acc[1][0], 0, 0, 0);
            acc[1][1] = __builtin_amdgcn_mfma_f32_16x16x32_bf16(al1, bh1, acc[1][1], 0, 0, 0);
        }
        // ---- per-lane top-2 update ----
        #pragma unroll
        for (int sm = 0; sm < 2; sm++) {
            #pragma unroll
            for (int sn = 0; sn < 2; sn++) {
                unsigned ci = (unsigned)((ch & 3)*64 + wn*32 + sn*16 + l15);
                #pragma unroll
                for (int r = 0; r < 4; r++) {
                    int ri = sm*4 + r;
                    float v = acc[sm][sn][r];
                    if (v > bv1[ri]) { bv2[ri] = bv1[ri]; bv1[ri] = v; bi1[ri] = ci; }
                    else if (v > bv2[ri]) bv2[ri] = v;
                    float nv = -v;
                    if (nv > bv1[ri]) { bv2[ri] = bv1[ri]; bv1[ri] = nv; bi1[ri] = 256u + ci; }
                    else if (nv > bv2[ri]) bv2[ri] = nv;
                }
            }
        }
        if ((ch & 3) == 3) {
            // ---- cross-lane butterfly over l15 bits (lanes sharing rows) ----
            #pragma unroll
            for (int i = 0; i < 8; i++) {
                #pragma unroll
                for (int d = 1; d < 16; d <<= 1) {
                    float ov1 = __shfl_xor(bv1[i], d);
                    unsigned oi1 = (unsigned)__shfl_xor((int)bi1[i], d);
                    float ov2 = __shfl_xor(bv2[i], d);
                    if (ov1 > bv1[i]) { bv2[i] = fmaxf(bv1[i], ov2); bv1[i] = ov1; bi1[i] = oi1; }
                    else if (ov1 < bv1[i]) { bv2[i] = fmaxf(bv2[i], ov1); }
                    else { bi1[i] = min(bi1[i], oi1); bv2[i] = bv1[i]; }
                }
            }
            if (l15 == 0) {
                #pragma unroll
                for (int i = 0; i < 8; i++) {
                    int rl = wm*32 + (i >> 2)*16 + l4*4 + (i & 3);
                    redv1[wn*64 + rl] = bv1[i];
                    redi1[wn*64 + rl] = bi1[i];
                    redv2[wn*64 + rl] = bv2[i];
                }
            }
            __syncthreads();
            if (tid < 64) {
                float v1 = redv1[tid], v2 = redv2[tid];
                unsigned i1 = redi1[tid];
                float w1 = redv1[64 + tid], w2 = redv2[64 + tid];
                unsigned j1 = redi1[64 + tid];
                float nv1, nv2; unsigned ni1;
                if (w1 > v1)      { nv1 = w1; ni1 = j1; nv2 = fmaxf(v1, w2); }
                else if (w1 < v1) { nv1 = v1; ni1 = i1; nv2 = fmaxf(v2, w1); }
                else              { nv1 = v1; ni1 = min(i1, j1); nv2 = v1; }
                bidx[tid] = ni1;
                bflag[tid] = (nv1 - nv2 < GAP_THR) ? 1 : 0;
            }
            __syncthreads();
            // ---- exact f32 fallback for flagged rows (rare) ----
            for (int r = 0; r < 64; r++) {
                if (bflag[r]) {
                    const float* qrow = qk + (size_t)(m0 + r) * 64;
                    const float* rc = rotT2 + (size_t)h * 16384 + tid;
                    float dsum = 0.f;
                    #pragma unroll 16
                    for (int k = 0; k < 64; k++) dsum += qrow[k] * rc[k * 256];
                    float mv; unsigned mi;
                    if (dsum >= -dsum) { mv = dsum; mi = (unsigned)tid; }
                    else               { mv = -dsum; mi = 256u + (unsigned)tid; }
                    fv[tid] = mv; fi[tid] = mi;
                    __syncthreads();
                    for (int s = 128; s > 0; s >>= 1) {
                        if (tid < s) {
                            float ov = fv[tid + s]; unsigned oi = fi[tid + s];
                            if (ov > fv[tid] || (ov == fv[tid] && oi < fi[tid])) { fv[tid] = ov; fi[tid] = oi; }
                        }
                        __syncthreads();
                    }
                    if (tid == 0) bidx[r] = fi[0];
                    __syncthreads();
                }
            }
            if (tid < 64) {
                int grow = m0 + tid;
                int bm = grow >> 11, t = grow & 2047;
                buckets[((size_t)(bm*4 + h))*2048 + t] = bidx[tid];
            }
        }
    }
}

// ---------------- K3: stable counting sort per (bm,hash) ----------------
__global__ __launch_bounds__(256) void k_sort(const unsigned* __restrict__ buckets,
                                              unsigned* __restrict__ st)
{
    __shared__ unsigned whist[4][512];
    __shared__ unsigned baseb[512];
    const int seg = blockIdx.x;                  // bm*4+h
    const unsigned* bk = buckets + (size_t)seg * 2048;
    unsigned* out = st + (size_t)seg * 2048;
    const int tid = threadIdx.x, w = tid >> 6, lane = tid & 63;
    for (int b = tid; b < 2048; b += 256) ((unsigned*)whist)[b] = 0u;
    __syncthreads();
    unsigned myb[8];
    #pragma unroll
    for (int r = 0; r < 8; r++) {
        int pos = w*512 + r*64 + lane;
        myb[r] = bk[pos];
        atomicAdd(&whist[w][myb[r]], 1u);
    }
    __syncthreads();
    for (int b = tid; b < 512; b += 256) {
        unsigned p = 0;
        #pragma unroll
        for (int ww = 0; ww < 4; ww++) { unsigned t = whist[ww][b]; whist[ww][b] = p; p += t; }
        baseb[b] = p;
    }
    __syncthreads();
    if (tid == 0) {
        unsigned run = 0;
        for (int b = 0; b < 512; b++) { unsigned t = baseb[b]; baseb[b] = run; run += t; }
    }
    __syncthreads();
    for (int b = tid; b < 512; b += 256) {
        unsigned bb = baseb[b];
        #pragma unroll
        for (int ww = 0; ww < 4; ww++) whist[ww][b] += bb;
    }
    __syncthreads();
    for (int r = 0; r < 8; r++) {
        unsigned b = myb[r];
        int pos = w*512 + r*64 + lane;
        unsigned base = whist[w][b];             // read before this round's bumps
        unsigned rank = 0;
        for (int j = 0; j < 64; j++) {
            unsigned bj = __shfl(b, j);
            rank += (j < lane && bj == b) ? 1u : 0u;
        }
        out[base + rank] = (unsigned)pos;
        atomicAdd(&whist[w][b], 1u);
    }
}

// ---------------- K4: chunked LSH attention (bf16 oh output) ----------------
__global__ __launch_bounds__(256) void k_attn(const float* __restrict__ qk,
    const float* __restrict__ vv, const float* __restrict__ rnorm,
    const unsigned* __restrict__ st, unsigned short* __restrict__ oh16,
    float* __restrict__ logits)
{
    __shared__ float qs[68][68];
    __shared__ float vs[68][68];
    __shared__ unsigned P[68];
    __shared__ float rn[68];
    const int sid = blockIdx.x;
    const int stripi = sid & 31;
    const int seg = sid >> 5;
    const int bm = seg >> 2, h = seg & 3;
    const int G0 = (h*512 + stripi*16) * 4;      // first q slot (global, 0..8191)
    const int tid = threadIdx.x;
    for (int j = tid; j < 68; j += 256) {
        int G = (G0 - 4 + j) & 8191;
        int hg = G >> 11, sg = G & 2047;
        unsigned tok = st[((size_t)(bm*4 + hg))*2048 + sg];
        P[j] = tok;
        rn[j] = rnorm[bm*2048 + (int)tok];
    }
    __syncthreads();
    for (int e = tid; e < 68*16; e += 256) {
        int j = e >> 4, fq = e & 15;
        unsigned tok = P[j];
        size_t base = ((size_t)(bm*2048 + (int)tok))*64 + fq*4;
        *(float4*)&qs[j][fq*4] = *(const float4*)(qk + base);
        *(float4*)&vs[j][fq*4] = *(const float4*)(vv + base);
    }
    __syncthreads();
    const int w = tid >> 6, lane = tid & 63;
    const int half = lane >> 5, qi = (lane >> 3) & 3, jj = lane & 7;
    const int fb = lane & 7;
    for (int cp = 0; cp < 2; cp++) {
        int c = w*4 + cp*2 + half;               // local chunk 0..15
        int jq = 4 + c*4 + qi;
        int jk = c*4 + jj;
        float dot = 0.f;
        #pragma unroll
        for (int fq = 0; fq < 16; fq++) {
            float4 q4 = *(float4*)&qs[jq][fq*4];
            float4 k4 = *(float4*)&qs[jk][fq*4];
            dot += q4.x*k4.x + q4.y*k4.y + q4.z*k4.z + q4.w*k4.w;
        }
        dot *= 0.125f * rn[jk];
        if (P[jq] == P[jk]) dot = SELF_VAL;
        float m = dot;
        m = fmaxf(m, __shfl_xor(m, 1));
        m = fmaxf(m, __shfl_xor(m, 2));
        m = fmaxf(m, __shfl_xor(m, 4));
        float ex = expf(dot - m);
        float s = ex;
        s += __shfl_xor(s, 1); s += __shfl_xor(s, 2); s += __shfl_xor(s, 4);
        float lse = m + logf(s);
        float p = expf(dot - lse);
        unsigned tq = P[jq];
        if (jj == 0) logits[((size_t)(bm*4 + h))*2048 + tq] = lse;
        float a0=0,a1=0,a2=0,a3=0,a4a=0,a5=0,a6=0,a7=0;
        #pragma unroll
        for (int j2 = 0; j2 < 8; j2++) {
            float pj = __shfl(p, (lane & 0x38) | j2);
            float4 va = *(float4*)&vs[c*4 + j2][fb*8];
            float4 vb = *(float4*)&vs[c*4 + j2][fb*8 + 4];
            a0 += pj*va.x; a1 += pj*va.y; a2 += pj*va.z; a3 += pj*va.w;
            a4a += pj*vb.x; a5 += pj*vb.y; a6 += pj*vb.z; a7 += pj*vb.w;
        }
        union { unsigned short s[8]; uint4 v; } ob;
        ob.s[0]=f2bf(a0); ob.s[1]=f2bf(a1); ob.s[2]=f2bf(a2); ob.s[3]=f2bf(a3);
        ob.s[4]=f2bf(a4a); ob.s[5]=f2bf(a5); ob.s[6]=f2bf(a6); ob.s[7]=f2bf(a7);
        *(uint4*)(oh16 + ((size_t)((bm*4 + h)*2048 + (int)tq))*64 + fb*8) = ob.v;
    }
}

// ---------------- K5: combine hash rounds (bf16 in, bf16 out) ----------------
__global__ __launch_bounds__(256) void k_combine(const unsigned short* __restrict__ oh16,
    const float* __restrict__ logits, unsigned short* __restrict__ comb16)
{
    int w = threadIdx.x >> 6, lane = threadIdx.x & 63;
    int row = blockIdx.x * 4 + w;                // bm*2048+t
    int bm = row >> 11, t = row & 2047;
    int b = bm >> 3, head = bm & 7;
    float l0 = logits[((size_t)(bm*4 + 0))*2048 + t];
    float l1 = logits[((size_t)(bm*4 + 1))*2048 + t];
    float l2 = logits[((size_t)(bm*4 + 2))*2048 + t];
    float l3 = logits[((size_t)(bm*4 + 3))*2048 + t];
    float m = fmaxf(fmaxf(l0, l1), fmaxf(l2, l3));
    float e0 = expf(l0 - m), e1 = expf(l1 - m), e2 = expf(l2 - m), e3 = expf(l3 - m);
    float inv = 1.0f / (e0 + e1 + e2 + e3);
    float o = 0.f;
    o += (e0*inv) * bf2f(oh16[((size_t)((bm*4+0)*2048 + t))*64 + lane]);
    o += (e1*inv) * bf2f(oh16[((size_t)((bm*4+1)*2048 + t))*64 + lane]);
    o += (e2*inv) * bf2f(oh16[((size_t)((bm*4+2)*2048 + t))*64 + lane]);
    o += (e3*inv) * bf2f(oh16[((size_t)((bm*4+3)*2048 + t))*64 + lane]);
    comb16[((size_t)(b*2048 + t))*512 + head*64 + lane] = f2bf(o);
}

// ---------------- K6: output GEMM + bias (bf16 MFMA, 64x64 block, 4 waves 2x2) ----------------
__global__ __launch_bounds__(256) void k_gemm_out(
    const unsigned short* __restrict__ comb16, const unsigned short* __restrict__ WoutT16,
    const float* __restrict__ bias, float* __restrict__ out)
{
    __shared__ unsigned short Asl[64*72];
    __shared__ unsigned short Bsl[64*72];
    const int bx = blockIdx.x;
    const int mt = bx >> 3, nt = bx & 7;
    const int m0 = mt*64, n0 = nt*64;
    const int tid = threadIdx.x;
    const int wid = tid >> 6, lane = tid & 63;
    const int wm = wid >> 1, wn = wid & 1;
    const int l15 = lane & 15, l4 = lane >> 4;
    const int srow = tid >> 2, skb = (tid & 3) * 16;
    f32x4 acc[2][2] = {};
    for (int k0 = 0; k0 < 512; k0 += 64) {
        {
            const unsigned short* asrc = comb16 + (size_t)(m0 + srow)*512 + k0 + skb;
            *(uint4*)&Asl[srow*72 + skb]     = *(const uint4*)asrc;
            *(uint4*)&Asl[srow*72 + skb + 8] = *(const uint4*)(asrc + 8);
            const unsigned short* bsrc = WoutT16 + (size_t)(n0 + srow)*512 + k0 + skb;
            *(uint4*)&Bsl[srow*72 + skb]     = *(const uint4*)bsrc;
            *(uint4*)&Bsl[srow*72 + skb + 8] = *(const uint4*)(bsrc + 8);
        }
        __syncthreads();
        #pragma unroll
        for (int kq = 0; kq < 2; kq++) {
            int kb = kq*32 + l4*8;
            bf16x8 a0 = *(bf16x8*)&Asl[(wm*32 +      l15)*72 + kb];
            bf16x8 a1 = *(bf16x8*)&Asl[(wm*32 + 16 + l15)*72 + kb];
            bf16x8 b0 = *(bf16x8*)&Bsl[(wn*32 +      l15)*72 + kb];
            bf16x8 b1 = *(bf16x8*)&Bsl[(wn*32 + 16 + l15)*72 + kb];
            acc[0][0] = __builtin_amdgcn_mfma_f32_16x16x32_bf16(a0, b0, acc[0][0], 0, 0, 0);
            acc[0][1] = __builtin_amdgcn_mfma_f32_16x16x32_bf16(a0, b1, acc[0][1], 0, 0, 0);
            acc[1][0] = __builtin_amdgcn_mfma_f32_16x16x32_bf16(a1, b0, acc[1][0], 0, 0, 0);
            acc[1][1] = __builtin_amdgcn_mfma_f32_16x16x32_bf16(a1, b1, acc[1][1], 0, 0, 0);
        }
        __syncthreads();
    }
    #pragma unroll
    for (int sm = 0; sm < 2; sm++) {
        #pragma unroll
        for (int sn = 0; sn < 2; sn++) {
            int col = n0 + wn*32 + sn*16 + l15;
            float bb = bias[col];
            #pragma unroll
            for (int r = 0; r < 4; r++) {
                int row = m0 + wm*32 + sm*16 + l4*4 + r;
                out[(size_t)row*512 + col] = acc[sm][sn][r] + bb;
            }
        }
    }
}

extern "C" void kernel_launch(void* const* d_in, const int* in_sizes, int n_in,
                              void* d_out, int out_size, void* d_ws, size_t ws_size,
                              hipStream_t stream)
{
    const float* Q    = (const float*)d_in[0];
    const float* Wqk  = (const float*)d_in[3];
    const float* Wv   = (const float*)d_in[4];
    const float* Wout = (const float*)d_in[5];
    const float* bout = (const float*)d_in[6];
    const float* rot  = (const float*)d_in[7];
    float* ws = (float*)d_ws;
    float* qk     = ws;                       // 8,388,608 floats
    float* vv     = ws + 8388608;             // 8,388,608
    unsigned short* oh16    = (unsigned short*)(ws + 16777216);  // 33.5M ushort
    unsigned short* WoutT16 = (unsigned short*)(ws + 33554432);  // 262144 ushort
    unsigned short* Q16     = (unsigned short*)(ws + 33685504);  // 8.4M ushort
    unsigned short* WvT16   = (unsigned short*)(ws + 37879808);  // 262144 ushort
    unsigned short* qk16hi  = (unsigned short*)(ws + 38010880);  // 8.4M ushort
    unsigned short* qk16lo  = (unsigned short*)(ws + 42205184);  // 8.4M ushort
    unsigned short* rotT3hi = (unsigned short*)(ws + 46399488);  // 65536 ushort
    unsigned short* rotT3lo = (unsigned short*)(ws + 46432256);  // 65536 ushort
    unsigned short* comb16  = (unsigned short*)(ws + 50331648);  // 16.7M ushort
    float* rnorm  = ws + 58720256;            // 131,072
    float* logits = ws + 58851328;            // 524,288
    unsigned* buckets = (unsigned*)(ws + 59375616);   // 524,288
    unsigned* st      = (unsigned*)(ws + 59899904);   // 524,288
    float* rotT2  = ws + 60424192;            // 65,536
    float* out = (float*)d_out;

    k_rotT    <<<dim3(256),  dim3(256), 0, stream>>>(rot, rotT2);
    k_rotsplit<<<dim3(256),  dim3(256), 0, stream>>>(rot, rotT3hi, rotT3lo);
    k_woutT   <<<dim3(1024), dim3(256), 0, stream>>>(Wout, WoutT16);
    k_wvT     <<<dim3(1024), dim3(256), 0, stream>>>(Wv, WvT16);
    k_q16     <<<dim3(4096), dim3(256), 0, stream>>>(Q, Q16);
    k_gemm_qk <<<dim3(512),  dim3(256), 0, stream>>>(Q, Wqk, qk, rnorm, qk16hi, qk16lo);
    k_gemm_v  <<<dim3(2048), dim3(256), 0, stream>>>(Q16, WvT16, vv);
    k_hash    <<<dim3(2048), dim3(256), 0, stream>>>(qk, qk16hi, qk16lo, rotT2, rotT3hi, rotT3lo, buckets);
    k_sort    <<<dim3(256),  dim3(256), 0, stream>>>(buckets, st);
    k_attn    <<<dim3(8192), dim3(256), 0, stream>>>(qk, vv, rnorm, st, oh16, logits);
    k_combine <<<dim3(32768),dim3(256), 0, stream>>>(oh16, logits, comb16);
    k_gemm_out<<<dim3(2048), dim3(256), 0, stream>>>(comb16, WoutT16, bout, out);
}

// Round 19
// 557.149 us; speedup vs baseline: 1.0863x; 1.0863x over previous
//
#include <hip/hip_runtime.h>
#include <math.h>

#define SELF_VAL (-5e4f)

typedef __attribute__((ext_vector_type(8))) short bf16x8;
typedef __attribute__((ext_vector_type(4))) float f32x4;

__device__ __forceinline__ unsigned short f2bf(float x) {
    unsigned b = __float_as_uint(x);
    b += 0x7FFFu + ((b >> 16) & 1u);
    return (unsigned short)(b >> 16);
}
__device__ __forceinline__ float bf2f(unsigned short h) {
    return __uint_as_float(((unsigned)h) << 16);
}

// ---------------- K0: re-layout rotations -> rotT2[h][k][col]  (4 x 64 x 256) ----------------
__global__ __launch_bounds__(256) void k_rotT(const float* __restrict__ rot,
                                              float* __restrict__ rotT2)
{
    int idx = blockIdx.x * 256 + threadIdx.x;    // 0..65535
    int h = idx >> 14, k = (idx >> 8) & 63, col = idx & 255;
    rotT2[idx] = rot[k * 1024 + h * 256 + col];
}

// ---------------- K0b: Wout -> transposed bf16 WoutT16[n][k] ----------------
__global__ __launch_bounds__(256) void k_woutT(const float* __restrict__ Wout,
                                               unsigned short* __restrict__ WoutT16)
{
    int idx = blockIdx.x * 256 + threadIdx.x;    // 0..262143
    int n = idx >> 9, k = idx & 511;
    WoutT16[idx] = f2bf(Wout[(size_t)k * 512 + n]);
}

// ---------------- K0c: Wv -> transposed bf16 WvT16[n][k] ----------------
__global__ __launch_bounds__(256) void k_wvT(const float* __restrict__ Wv,
                                             unsigned short* __restrict__ WvT16)
{
    int idx = blockIdx.x * 256 + threadIdx.x;    // 0..262143
    int n = idx >> 9, k = idx & 511;
    WvT16[idx] = f2bf(Wv[(size_t)k * 512 + n]);
}

// ---------------- K0d: Q -> bf16 row-major Q16 ----------------
__global__ __launch_bounds__(256) void k_q16(const float* __restrict__ Q,
                                             unsigned short* __restrict__ Q16)
{
    int idx = blockIdx.x * 256 + threadIdx.x;    // 8 elems each
    const float* src = Q + (size_t)idx * 8;
    float4 v0 = *(const float4*)src;
    float4 v1 = *(const float4*)(src + 4);
    union { unsigned short s[8]; uint4 v; } ob;
    ob.s[0]=f2bf(v0.x); ob.s[1]=f2bf(v0.y); ob.s[2]=f2bf(v0.z); ob.s[3]=f2bf(v0.w);
    ob.s[4]=f2bf(v1.x); ob.s[5]=f2bf(v1.y); ob.s[6]=f2bf(v1.z); ob.s[7]=f2bf(v1.w);
    *(uint4*)(Q16 + (size_t)idx * 8) = ob.v;
}

// ---------------- K1: qk GEMM (f32, 128x128, 8x8/thread, T14 dbuf) + fused rnorm ----------------
// N=512 (Wqk only) — the hash path needs full f32 precision.
__global__ __launch_bounds__(256) void k_gemm_qk(
    const float* __restrict__ Q, const float* __restrict__ Wqk,
    float* __restrict__ qk, float* __restrict__ rnorm)
{
    __shared__ float As[16][132];   // transposed: As[k][m]
    __shared__ float Bs[16][132];
    const int bx = blockIdx.x;
    const int mt = bx >> 2, nt = bx & 3;
    const int m0 = mt * 128, n0 = nt * 128;
    const int tid = threadIdx.x;
    const int ty = tid >> 4, tx = tid & 15;
    const float* Bsrc = Wqk + n0;
    const int ar0 = tid >> 2, acq = (tid & 3) * 4;
    const int ar1 = 64 + (tid >> 2);
    const int bk0 = tid >> 5, bnq = (tid & 31) * 4;
    const int bk1 = 8 + (tid >> 5);
    const float* Aptr0 = Q + (size_t)(m0 + ar0) * 512 + acq;
    const float* Aptr1 = Q + (size_t)(m0 + ar1) * 512 + acq;
    const float* Bptr0 = Bsrc + (size_t)bk0 * 512 + bnq;
    const float* Bptr1 = Bsrc + (size_t)bk1 * 512 + bnq;
    float acc[8][8] = {};
    float4 a0 = *(const float4*)(Aptr0);
    float4 a1 = *(const float4*)(Aptr1);
    float4 b0 = *(const float4*)(Bptr0);
    float4 b1 = *(const float4*)(Bptr1);
    for (int k0 = 0; k0 < 512; k0 += 16) {
        As[acq+0][ar0]=a0.x; As[acq+1][ar0]=a0.y; As[acq+2][ar0]=a0.z; As[acq+3][ar0]=a0.w;
        As[acq+0][ar1]=a1.x; As[acq+1][ar1]=a1.y; As[acq+2][ar1]=a1.z; As[acq+3][ar1]=a1.w;
        *(float4*)&Bs[bk0][bnq] = b0;
        *(float4*)&Bs[bk1][bnq] = b1;
        __syncthreads();
        if (k0 + 16 < 512) {
            a0 = *(const float4*)(Aptr0 + k0 + 16);
            a1 = *(const float4*)(Aptr1 + k0 + 16);
            b0 = *(const float4*)(Bptr0 + (size_t)(k0 + 16) * 512);
            b1 = *(const float4*)(Bptr1 + (size_t)(k0 + 16) * 512);
        }
        #pragma unroll
        for (int kk = 0; kk < 16; kk++) {
            float a_[8], b_[8];
            *(float4*)&a_[0] = *(float4*)&As[kk][ty*4];
            *(float4*)&a_[4] = *(float4*)&As[kk][64 + ty*4];
            *(float4*)&b_[0] = *(float4*)&Bs[kk][tx*4];
            *(float4*)&b_[4] = *(float4*)&Bs[kk][64 + tx*4];
            #pragma unroll
            for (int i = 0; i < 8; i++)
                #pragma unroll
                for (int j = 0; j < 8; j++)
                    acc[i][j] += a_[i] * b_[j];
        }
        __syncthreads();
    }
    #pragma unroll
    for (int ig = 0; ig < 2; ig++) {
        #pragma unroll
        for (int i = 0; i < 4; i++) {
            int row = m0 + ig*64 + ty*4 + i;
            int b = row >> 11, t = row & 2047;
            #pragma unroll
            for (int jg = 0; jg < 2; jg++) {
                int n = n0 + jg*64 + tx*4;
                float4 r4 = make_float4(acc[ig*4+i][jg*4+0], acc[ig*4+i][jg*4+1],
                                        acc[ig*4+i][jg*4+2], acc[ig*4+i][jg*4+3]);
                *(float4*)(qk + ((size_t)((b*8 + (n>>6))*2048 + t))*64 + (n&63)) = r4;
            }
        }
    }
    // ---- fused rnorm: 2 heads x 128 tokens per block ----
    #pragma unroll
    for (int jg = 0; jg < 2; jg++) {
        int h = (n0 + jg*64) >> 6;
        #pragma unroll
        for (int ig = 0; ig < 2; ig++) {
            #pragma unroll
            for (int i = 0; i < 4; i++) {
                float s = acc[ig*4+i][jg*4+0]*acc[ig*4+i][jg*4+0]
                        + acc[ig*4+i][jg*4+1]*acc[ig*4+i][jg*4+1]
                        + acc[ig*4+i][jg*4+2]*acc[ig*4+i][jg*4+2]
                        + acc[ig*4+i][jg*4+3]*acc[ig*4+i][jg*4+3];
                s += __shfl_xor(s, 1);
                s += __shfl_xor(s, 2);
                s += __shfl_xor(s, 4);
                s += __shfl_xor(s, 8);
                if (tx == 0) {
                    int row = m0 + ig*64 + ty*4 + i;
                    int b = row >> 11, t = row & 2047;
                    rnorm[((size_t)(b*8 + h))*2048 + t] = 1.0f / fmaxf(sqrtf(s), 1e-12f);
                }
            }
        }
    }
}

// ---------------- K1b: v GEMM (bf16 MFMA, 64x64 block, 4 waves 2x2) ----------------
// A = Q16 [16384][512]; B = WvT16 [n][k]; writes vv f32 head-major.
__global__ __launch_bounds__(256) void k_gemm_v(
    const unsigned short* __restrict__ Q16, const unsigned short* __restrict__ WvT16,
    float* __restrict__ vv)
{
    __shared__ unsigned short Asl[64*72];
    __shared__ unsigned short Bsl[64*72];
    const int bx = blockIdx.x;
    const int mt = bx >> 3, nt = bx & 7;
    const int m0 = mt*64, n0 = nt*64;
    const int tid = threadIdx.x;
    const int wid = tid >> 6, lane = tid & 63;
    const int wm = wid >> 1, wn = wid & 1;
    const int l15 = lane & 15, l4 = lane >> 4;
    const int srow = tid >> 2, skb = (tid & 3) * 16;
    f32x4 acc[2][2] = {};
    for (int k0 = 0; k0 < 512; k0 += 64) {
        {
            const unsigned short* asrc = Q16 + (size_t)(m0 + srow)*512 + k0 + skb;
            *(uint4*)&Asl[srow*72 + skb]     = *(const uint4*)asrc;
            *(uint4*)&Asl[srow*72 + skb + 8] = *(const uint4*)(asrc + 8);
            const unsigned short* bsrc = WvT16 + (size_t)(n0 + srow)*512 + k0 + skb;
            *(uint4*)&Bsl[srow*72 + skb]     = *(const uint4*)bsrc;
            *(uint4*)&Bsl[srow*72 + skb + 8] = *(const uint4*)(bsrc + 8);
        }
        __syncthreads();
        #pragma unroll
        for (int kq = 0; kq < 2; kq++) {
            int kb = kq*32 + l4*8;
            bf16x8 a0 = *(bf16x8*)&Asl[(wm*32 +      l15)*72 + kb];
            bf16x8 a1 = *(bf16x8*)&Asl[(wm*32 + 16 + l15)*72 + kb];
            bf16x8 b0 = *(bf16x8*)&Bsl[(wn*32 +      l15)*72 + kb];
            bf16x8 b1 = *(bf16x8*)&Bsl[(wn*32 + 16 + l15)*72 + kb];
            acc[0][0] = __builtin_amdgcn_mfma_f32_16x16x32_bf16(a0, b0, acc[0][0], 0, 0, 0);
            acc[0][1] = __builtin_amdgcn_mfma_f32_16x16x32_bf16(a0, b1, acc[0][1], 0, 0, 0);
            acc[1][0] = __builtin_amdgcn_mfma_f32_16x16x32_bf16(a1, b0, acc[1][0], 0, 0, 0);
            acc[1][1] = __builtin_amdgcn_mfma_f32_16x16x32_bf16(a1, b1, acc[1][1], 0, 0, 0);
        }
        __syncthreads();
    }
    #pragma unroll
    for (int sm = 0; sm < 2; sm++) {
        #pragma unroll
        for (int sn = 0; sn < 2; sn++) {
            int col = n0 + wn*32 + sn*16 + l15;
            int h = col >> 6, d = col & 63;
            #pragma unroll
            for (int r = 0; r < 4; r++) {
                int row = m0 + wm*32 + sm*16 + l4*4 + r;
                int b = row >> 11, t = row & 2047;
                vv[((size_t)((b*8 + h)*2048 + t))*64 + d] = acc[sm][sn][r];
            }
        }
    }
}

// ---------------- K2: hash = f32 GEMM (128 tokens, K=64) + signed argmax ----------------
// FROZEN round-6 body (287 us, VGPR 64, VALUBusy 70%) — 7 optimization attempts
// all regressed; this is the structural floor for this op.
__global__ __launch_bounds__(256) void k_hash(const float* __restrict__ qk,
    const float* __restrict__ rotT2, unsigned* __restrict__ buckets)
{
    __shared__ float As[64*128];    // As[k][row], pitch 128 (32 KB)
    const int bx = blockIdx.x;
    const int bm = bx >> 4;
    const int row0 = (bx & 15) << 7;             // token base within bm
    const int tid = threadIdx.x;
    const int ty = tid >> 4, tx = tid & 15;
    {
        const int r = tid >> 1;
        const int kb = (tid & 1) * 8;            // float4 units
        const float* src = qk + ((size_t)(bm*2048 + row0 + r))*64;
        #pragma unroll
        for (int c = 0; c < 8; c++) {
            float4 a4 = *(const float4*)(src + (size_t)(kb + c)*4);
            int k = (kb + c)*4;
            As[(k+0)*128 + r] = a4.x;
            As[(k+1)*128 + r] = a4.y;
            As[(k+2)*128 + r] = a4.z;
            As[(k+3)*128 + r] = a4.w;
        }
    }
    __syncthreads();
    #pragma unroll 1
    for (int h = 0; h < 4; h++) {
        float bv[8]; unsigned bi[8];
        #pragma unroll
        for (int i = 0; i < 8; i++) { bv[i] = -3.402823466e38f; bi[i] = 0u; }
        #pragma unroll 1
        for (int ch = 0; ch < 4; ch++) {
            const float* bsrc = rotT2 + (size_t)h*16384 + ch*64 + tx*4;
            float acc[8][4] = {};
            #pragma unroll 16
            for (int kk = 0; kk < 64; kk++) {
                float4 b4 = *(const float4*)(bsrc + (size_t)kk*256);
                float a_[8];
                *(float4*)&a_[0] = *(float4*)&As[kk*128 + ty*4];
                *(float4*)&a_[4] = *(float4*)&As[kk*128 + 64 + ty*4];
                float b_[4] = {b4.x, b4.y, b4.z, b4.w};
                #pragma unroll
                for (int i = 0; i < 8; i++)
                    #pragma unroll
                    for (int j = 0; j < 4; j++)
                        acc[i][j] += a_[i] * b_[j];
            }
            #pragma unroll
            for (int j = 0; j < 4; j++) {
                unsigned c0 = (unsigned)(ch*64 + tx*4 + j);
                unsigned nc0 = 256u + c0;
                #pragma unroll
                for (int i = 0; i < 8; i++) {
                    float v = acc[i][j];
                    if (v > bv[i] || (v == bv[i] && c0 < bi[i])) { bv[i] = v; bi[i] = c0; }
                    float nv = -v;
                    if (nv > bv[i] || (nv == bv[i] && nc0 < bi[i])) { bv[i] = nv; bi[i] = nc0; }
                }
            }
        }
        #pragma unroll
        for (int i = 0; i < 8; i++) {
            #pragma unroll
            for (int d = 1; d < 16; d <<= 1) {
                float ov = __shfl_xor(bv[i], d);
                unsigned oi = (unsigned)__shfl_xor((int)bi[i], d);
                if (ov > bv[i] || (ov == bv[i] && oi < bi[i])) { bv[i] = ov; bi[i] = oi; }
            }
        }
        if (tx == 0) {
            #pragma unroll
            for (int i = 0; i < 8; i++) {
                int r = (i < 4) ? (ty*4 + i) : (64 + ty*4 + (i - 4));
                buckets[((size_t)(bm*4 + h))*2048 + row0 + r] = bi[i];
            }
        }
    }
}

// ---------------- K3: stable counting sort per (bm,hash) ----------------
__global__ __launch_bounds__(256) void k_sort(const unsigned* __restrict__ buckets,
                                              unsigned* __restrict__ st)
{
    __shared__ unsigned whist[4][512];
    __shared__ unsigned baseb[512];
    const int seg = blockIdx.x;                  // bm*4+h
    const unsigned* bk = buckets + (size_t)seg * 2048;
    unsigned* out = st + (size_t)seg * 2048;
    const int tid = threadIdx.x, w = tid >> 6, lane = tid & 63;
    for (int b = tid; b < 2048; b += 256) ((unsigned*)whist)[b] = 0u;
    __syncthreads();
    unsigned myb[8];
    #pragma unroll
    for (int r = 0; r < 8; r++) {
        int pos = w*512 + r*64 + lane;
        myb[r] = bk[pos];
        atomicAdd(&whist[w][myb[r]], 1u);
    }
    __syncthreads();
    for (int b = tid; b < 512; b += 256) {
        unsigned p = 0;
        #pragma unroll
        for (int ww = 0; ww < 4; ww++) { unsigned t = whist[ww][b]; whist[ww][b] = p; p += t; }
        baseb[b] = p;
    }
    __syncthreads();
    if (tid == 0) {
        unsigned run = 0;
        for (int b = 0; b < 512; b++) { unsigned t = baseb[b]; baseb[b] = run; run += t; }
    }
    __syncthreads();
    for (int b = tid; b < 512; b += 256) {
        unsigned bb = baseb[b];
        #pragma unroll
        for (int ww = 0; ww < 4; ww++) whist[ww][b] += bb;
    }
    __syncthreads();
    for (int r = 0; r < 8; r++) {
        unsigned b = myb[r];
        int pos = w*512 + r*64 + lane;
        unsigned base = whist[w][b];             // read before this round's bumps
        unsigned rank = 0;
        for (int j = 0; j < 64; j++) {
            unsigned bj = __shfl(b, j);
            rank += (j < lane && bj == b) ? 1u : 0u;
        }
        out[base + rank] = (unsigned)pos;
        atomicAdd(&whist[w][b], 1u);
    }
}

// ---------------- K4: chunked LSH attention (bf16 oh output) ----------------
__global__ __launch_bounds__(256) void k_attn(const float* __restrict__ qk,
    const float* __restrict__ vv, const float* __restrict__ rnorm,
    const unsigned* __restrict__ st, unsigned short* __restrict__ oh16,
    float* __restrict__ logits)
{
    __shared__ float qs[68][68];
    __shared__ float vs[68][68];
    __shared__ unsigned P[68];
    __shared__ float rn[68];
    const int sid = blockIdx.x;
    const int stripi = sid & 31;
    const int seg = sid >> 5;
    const int bm = seg >> 2, h = seg & 3;
    const int G0 = (h*512 + stripi*16) * 4;      // first q slot (global, 0..8191)
    const int tid = threadIdx.x;
    for (int j = tid; j < 68; j += 256) {
        int G = (G0 - 4 + j) & 8191;
        int hg = G >> 11, sg = G & 2047;
        unsigned tok = st[((size_t)(bm*4 + hg))*2048 + sg];
        P[j] = tok;
        rn[j] = rnorm[bm*2048 + (int)tok];
    }
    __syncthreads();
    for (int e = tid; e < 68*16; e += 256) {
        int j = e >> 4, fq = e & 15;
        unsigned tok = P[j];
        size_t base = ((size_t)(bm*2048 + (int)tok))*64 + fq*4;
        *(float4*)&qs[j][fq*4] = *(const float4*)(qk + base);
        *(float4*)&vs[j][fq*4] = *(const float4*)(vv + base);
    }
    __syncthreads();
    const int w = tid >> 6, lane = tid & 63;
    const int half = lane >> 5, qi = (lane >> 3) & 3, jj = lane & 7;
    const int fb = lane & 7;
    for (int cp = 0; cp < 2; cp++) {
        int c = w*4 + cp*2 + half;               // local chunk 0..15
        int jq = 4 + c*4 + qi;
        int jk = c*4 + jj;
        float dot = 0.f;
        #pragma unroll
        for (int fq = 0; fq < 16; fq++) {
            float4 q4 = *(float4*)&qs[jq][fq*4];
            float4 k4 = *(float4*)&qs[jk][fq*4];
            dot += q4.x*k4.x + q4.y*k4.y + q4.z*k4.z + q4.w*k4.w;
        }
        dot *= 0.125f * rn[jk];
        if (P[jq] == P[jk]) dot = SELF_VAL;
        float m = dot;
        m = fmaxf(m, __shfl_xor(m, 1));
        m = fmaxf(m, __shfl_xor(m, 2));
        m = fmaxf(m, __shfl_xor(m, 4));
        float ex = expf(dot - m);
        float s = ex;
        s += __shfl_xor(s, 1); s += __shfl_xor(s, 2); s += __shfl_xor(s, 4);
        float lse = m + logf(s);
        float p = expf(dot - lse);
        unsigned tq = P[jq];
        if (jj == 0) logits[((size_t)(bm*4 + h))*2048 + tq] = lse;
        float a0=0,a1=0,a2=0,a3=0,a4a=0,a5=0,a6=0,a7=0;
        #pragma unroll
        for (int j2 = 0; j2 < 8; j2++) {
            float pj = __shfl(p, (lane & 0x38) | j2);
            float4 va = *(float4*)&vs[c*4 + j2][fb*8];
            float4 vb = *(float4*)&vs[c*4 + j2][fb*8 + 4];
            a0 += pj*va.x; a1 += pj*va.y; a2 += pj*va.z; a3 += pj*va.w;
            a4a += pj*vb.x; a5 += pj*vb.y; a6 += pj*vb.z; a7 += pj*vb.w;
        }
        union { unsigned short s[8]; uint4 v; } ob;
        ob.s[0]=f2bf(a0); ob.s[1]=f2bf(a1); ob.s[2]=f2bf(a2); ob.s[3]=f2bf(a3);
        ob.s[4]=f2bf(a4a); ob.s[5]=f2bf(a5); ob.s[6]=f2bf(a6); ob.s[7]=f2bf(a7);
        *(uint4*)(oh16 + ((size_t)((bm*4 + h)*2048 + (int)tq))*64 + fb*8) = ob.v;
    }
}

// ---------------- K5: combine hash rounds (bf16 in, bf16 out) ----------------
__global__ __launch_bounds__(256) void k_combine(const unsigned short* __restrict__ oh16,
    const float* __restrict__ logits, unsigned short* __restrict__ comb16)
{
    int w = threadIdx.x >> 6, lane = threadIdx.x & 63;
    int row = blockIdx.x * 4 + w;                // bm*2048+t
    int bm = row >> 11, t = row & 2047;
    int b = bm >> 3, head = bm & 7;
    float l0 = logits[((size_t)(bm*4 + 0))*2048 + t];
    float l1 = logits[((size_t)(bm*4 + 1))*2048 + t];
    float l2 = logits[((size_t)(bm*4 + 2))*2048 + t];
    float l3 = logits[((size_t)(bm*4 + 3))*2048 + t];
    float m = fmaxf(fmaxf(l0, l1), fmaxf(l2, l3));
    float e0 = expf(l0 - m), e1 = expf(l1 - m), e2 = expf(l2 - m), e3 = expf(l3 - m);
    float inv = 1.0f / (e0 + e1 + e2 + e3);
    float o = 0.f;
    o += (e0*inv) * bf2f(oh16[((size_t)((bm*4+0)*2048 + t))*64 + lane]);
    o += (e1*inv) * bf2f(oh16[((size_t)((bm*4+1)*2048 + t))*64 + lane]);
    o += (e2*inv) * bf2f(oh16[((size_t)((bm*4+2)*2048 + t))*64 + lane]);
    o += (e3*inv) * bf2f(oh16[((size_t)((bm*4+3)*2048 + t))*64 + lane]);
    comb16[((size_t)(b*2048 + t))*512 + head*64 + lane] = f2bf(o);
}

// ---------------- K6: output GEMM + bias (bf16 MFMA, 64x64 block, 4 waves 2x2) ----------------
__global__ __launch_bounds__(256) void k_gemm_out(
    const unsigned short* __restrict__ comb16, const unsigned short* __restrict__ WoutT16,
    const float* __restrict__ bias, float* __restrict__ out)
{
    __shared__ unsigned short Asl[64*72];
    __shared__ unsigned short Bsl[64*72];
    const int bx = blockIdx.x;
    const int mt = bx >> 3, nt = bx & 7;
    const int m0 = mt*64, n0 = nt*64;
    const int tid = threadIdx.x;
    const int wid = tid >> 6, lane = tid & 63;
    const int wm = wid >> 1, wn = wid & 1;
    const int l15 = lane & 15, l4 = lane >> 4;
    const int srow = tid >> 2, skb = (tid & 3) * 16;
    f32x4 acc[2][2] = {};
    for (int k0 = 0; k0 < 512; k0 += 64) {
        {
            const unsigned short* asrc = comb16 + (size_t)(m0 + srow)*512 + k0 + skb;
            *(uint4*)&Asl[srow*72 + skb]     = *(const uint4*)asrc;
            *(uint4*)&Asl[srow*72 + skb + 8] = *(const uint4*)(asrc + 8);
            const unsigned short* bsrc = WoutT16 + (size_t)(n0 + srow)*512 + k0 + skb;
            *(uint4*)&Bsl[srow*72 + skb]     = *(const uint4*)bsrc;
            *(uint4*)&Bsl[srow*72 + skb + 8] = *(const uint4*)(bsrc + 8);
        }
        __syncthreads();
        #pragma unroll
        for (int kq = 0; kq < 2; kq++) {
            int kb = kq*32 + l4*8;
            bf16x8 a0 = *(bf16x8*)&Asl[(wm*32 +      l15)*72 + kb];
            bf16x8 a1 = *(bf16x8*)&Asl[(wm*32 + 16 + l15)*72 + kb];
            bf16x8 b0 = *(bf16x8*)&Bsl[(wn*32 +      l15)*72 + kb];
            bf16x8 b1 = *(bf16x8*)&Bsl[(wn*32 + 16 + l15)*72 + kb];
            acc[0][0] = __builtin_amdgcn_mfma_f32_16x16x32_bf16(a0, b0, acc[0][0], 0, 0, 0);
            acc[0][1] = __builtin_amdgcn_mfma_f32_16x16x32_bf16(a0, b1, acc[0][1], 0, 0, 0);
            acc[1][0] = __builtin_amdgcn_mfma_f32_16x16x32_bf16(a1, b0, acc[1][0], 0, 0, 0);
            acc[1][1] = __builtin_amdgcn_mfma_f32_16x16x32_bf16(a1, b1, acc[1][1], 0, 0, 0);
        }
        __syncthreads();
    }
    #pragma unroll
    for (int sm = 0; sm < 2; sm++) {
        #pragma unroll
        for (int sn = 0; sn < 2; sn++) {
            int col = n0 + wn*32 + sn*16 + l15;
            float bb = bias[col];
            #pragma unroll
            for (int r = 0; r < 4; r++) {
                int row = m0 + wm*32 + sm*16 + l4*4 + r;
                out[(size_t)row*512 + col] = acc[sm][sn][r] + bb;
            }
        }
    }
}

extern "C" void kernel_launch(void* const* d_in, const int* in_sizes, int n_in,
                              void* d_out, int out_size, void* d_ws, size_t ws_size,
                              hipStream_t stream)
{
    const float* Q    = (const float*)d_in[0];
    const float* Wqk  = (const float*)d_in[3];
    const float* Wv   = (const float*)d_in[4];
    const float* Wout = (const float*)d_in[5];
    const float* bout = (const float*)d_in[6];
    const float* rot  = (const float*)d_in[7];
    float* ws = (float*)d_ws;
    float* qk     = ws;                       // 8,388,608 floats
    float* vv     = ws + 8388608;             // 8,388,608
    unsigned short* oh16 = (unsigned short*)(ws + 16777216);     // 33.5M ushort
    unsigned short* WoutT16 = (unsigned short*)(ws + 33554432);  // 262144 ushort
    unsigned short* Q16     = (unsigned short*)(ws + 33685504);  // 8.4M ushort
    unsigned short* WvT16   = (unsigned short*)(ws + 37879808);  // 262144 ushort
    unsigned short* comb16  = (unsigned short*)(ws + 50331648);  // 16.7M ushort
    float* rnorm  = ws + 58720256;            // 131,072
    float* logits = ws + 58851328;            // 524,288
    unsigned* buckets = (unsigned*)(ws + 59375616);   // 524,288
    unsigned* st      = (unsigned*)(ws + 59899904);   // 524,288
    float* rotT2  = ws + 60424192;            // 65,536
    float* out = (float*)d_out;

    k_rotT    <<<dim3(256),  dim3(256), 0, stream>>>(rot, rotT2);
    k_woutT   <<<dim3(1024), dim3(256), 0, stream>>>(Wout, WoutT16);
    k_wvT     <<<dim3(1024), dim3(256), 0, stream>>>(Wv, WvT16);
    k_q16     <<<dim3(4096), dim3(256), 0, stream>>>(Q, Q16);
    k_gemm_qk <<<dim3(512),  dim3(256), 0, stream>>>(Q, Wqk, qk, rnorm);
    k_gemm_v  <<<dim3(2048), dim3(256), 0, stream>>>(Q16, WvT16, vv);
    k_hash    <<<dim3(1024), dim3(256), 0, stream>>>(qk, rotT2, buckets);
    k_sort    <<<dim3(256),  dim3(256), 0, stream>>>(buckets, st);
    k_attn    <<<dim3(8192), dim3(256), 0, stream>>>(qk, vv, rnorm, st, oh16, logits);
    k_combine <<<dim3(32768),dim3(256), 0, stream>>>(oh16, logits, comb16);
    k_gemm_out<<<dim3(2048), dim3(256), 0, stream>>>(comb16, WoutT16, bout, out);
}